// Round 4
// baseline (483.495 us; speedup 1.0000x reference)
//
#include <hip/hip_runtime.h>

typedef unsigned short u16;
typedef __bf16 bf16x8 __attribute__((ext_vector_type(8)));
typedef float f32x4 __attribute__((ext_vector_type(4)));

constexpr int B_ = 2, T_ = 2048, D_ = 2048, H_ = 16, HD_ = 128;
constexpr int MROWS = B_ * T_;   // 4096
constexpr int KD = D_;
constexpr int ND = D_;
// softmax in exp2 domain: logits pre-scaled by 1/sqrt(128) * log2(e)
#define SL2E (0.08838834764831845f * 1.4426950408889634f)

__device__ __forceinline__ u16 f2bf(float f) {
  unsigned u = __float_as_uint(f);
  u += 0x7FFF + ((u >> 16) & 1);   // RNE; inputs never NaN
  return (u16)(u >> 16);
}

__device__ __forceinline__ float fexp2(float x) { return __builtin_amdgcn_exp2f(x); }

// async global->LDS, 16B per lane (contiguous dest only — GEMM staging)
__device__ __forceinline__ void async16(const void* g, void* l) {
  __builtin_amdgcn_global_load_lds((__attribute__((address_space(1))) void*)g,
                                   (__attribute__((address_space(3))) void*)l,
                                   16, 0, 0);
}

__global__ void cvt_kernel(const float* __restrict__ in, u16* __restrict__ out, int n) {
  int i = (blockIdx.x * blockDim.x + threadIdx.x) * 4;
  if (i >= n) return;
  const float4 v = *(const float4*)(in + i);
  ushort4 h;
  h.x = f2bf(v.x); h.y = f2bf(v.y); h.z = f2bf(v.z); h.w = f2bf(v.w);
  *(ushort4*)(out + i) = h;
}

__global__ void cvt4_kernel(const float* __restrict__ w0, const float* __restrict__ w1,
                            const float* __restrict__ w2, const float* __restrict__ w3,
                            u16* __restrict__ o0, u16* __restrict__ o1,
                            u16* __restrict__ o2, u16* __restrict__ o3, int n) {
  const float* in = blockIdx.y == 0 ? w0 : blockIdx.y == 1 ? w1 : blockIdx.y == 2 ? w2 : w3;
  u16* out = blockIdx.y == 0 ? o0 : blockIdx.y == 1 ? o1 : blockIdx.y == 2 ? o2 : o3;
  int i = (blockIdx.x * blockDim.x + threadIdx.x) * 4;
  if (i >= n) return;
  const float4 v = *(const float4*)(in + i);
  ushort4 h;
  h.x = f2bf(v.x); h.y = f2bf(v.y); h.z = f2bf(v.z); h.w = f2bf(v.w);
  *(ushort4*)(out + i) = h;
}

// ---- GEMM core: C = A @ Bw^T + bias. A:[M,K] bf16 rm, Bw:[N,K] bf16 rm. ----
// LDS tiles XOR-swizzled (conflict-free b128 column reads, verified R3:
// SQ_LDS_BANK_CONFLICT == 0).
template <int MODE>
__device__ __forceinline__ void gemm_body(const u16* __restrict__ A,
                                          const u16* __restrict__ Bw,
                                          const float* __restrict__ bias,
                                          void* __restrict__ outp,
                                          u16* As, u16* Bs) {
  constexpr int BK = 32;
  const int tid = threadIdx.x;
  const int wave = tid >> 6;
  const int lane = tid & 63;
  const int quad = lane >> 4;
  const int l16 = lane & 15;
  const int wm = (wave >> 1) * 64;
  const int wn = (wave & 1) * 64;
  const int mBase = blockIdx.y * 128;
  const int nBase = blockIdx.x * 128;

  f32x4 acc[4][4] = {};

  const int srow = wave * 32 + (lane >> 2);
  const int soff = ((lane & 3) ^ ((lane >> 3) & 3)) * 8;
  const u16* Ag = A + (size_t)(mBase + srow) * KD + soff;
  const u16* Bg = Bw + (size_t)(nBase + srow) * KD + soff;
  u16* AsW0 = &As[(wave * 32) * BK];
  u16* AsW1 = &As[(wave * 32 + 16) * BK];
  u16* BsW0 = &Bs[(wave * 32) * BK];
  u16* BsW1 = &Bs[(wave * 32 + 16) * BK];

  const int sw = (quad ^ ((l16 >> 1) & 3)) * 8;

  for (int k0 = 0; k0 < KD; k0 += BK) {
    __syncthreads();
    async16(Ag + k0, AsW0);
    async16(Ag + 16 * KD + k0, AsW1);
    async16(Bg + k0, BsW0);
    async16(Bg + 16 * KD + k0, BsW1);
    __syncthreads();

    bf16x8 a[4], b[4];
#pragma unroll
    for (int i = 0; i < 4; i++)
      a[i] = *(const bf16x8*)&As[(wm + i * 16 + l16) * BK + sw];
#pragma unroll
    for (int j = 0; j < 4; j++)
      b[j] = *(const bf16x8*)&Bs[(wn + j * 16 + l16) * BK + sw];
#pragma unroll
    for (int i = 0; i < 4; i++)
#pragma unroll
      for (int j = 0; j < 4; j++)
        acc[i][j] = __builtin_amdgcn_mfma_f32_16x16x32_bf16(a[i], b[j], acc[i][j], 0, 0, 0);
  }

  float* outF = (float*)outp;
  u16* outH = (u16*)outp;
#pragma unroll
  for (int i = 0; i < 4; i++) {
#pragma unroll
    for (int j = 0; j < 4; j++) {
      const int col = nBase + wn + j * 16 + l16;
      const float bv = bias[col];
#pragma unroll
      for (int r = 0; r < 4; r++) {
        const int row = mBase + wm + i * 16 + quad * 4 + r;
        const float v = acc[i][j][r] + bv;
        if (MODE == 0) {
          outH[(size_t)row * ND + col] = f2bf(v);
        } else if (MODE == 1) {
          const int bb = row >> 11;
          const int t = row & (T_ - 1);
          const int h = col >> 7;
          const int d = col & (HD_ - 1);
          outH[(size_t)(((bb * H_ + h) << 7) + d) * T_ + t] = f2bf(v);
        } else {
          outF[(size_t)row * ND + col] = v;
        }
      }
    }
  }
}

__global__ __launch_bounds__(256) void gemm_qkv(const u16* __restrict__ A,
                                                const u16* __restrict__ Wq, const u16* __restrict__ Wk,
                                                const u16* __restrict__ Wv,
                                                const float* __restrict__ bq, const float* __restrict__ bk,
                                                const float* __restrict__ bv,
                                                u16* __restrict__ Qo, u16* __restrict__ Ko,
                                                u16* __restrict__ Vo) {
  __shared__ u16 As[128 * 32];
  __shared__ u16 Bs[128 * 32];
  const int z = blockIdx.z;
  const u16* Bw = z == 0 ? Wq : z == 1 ? Wk : Wv;
  const float* bias = z == 0 ? bq : z == 1 ? bk : bv;
  if (z == 2)
    gemm_body<1>(A, Bw, bias, (void*)Vo, As, Bs);
  else
    gemm_body<0>(A, Bw, bias, (void*)(z == 0 ? Qo : Ko), As, Bs);
}

__global__ __launch_bounds__(256) void gemm_out(const u16* __restrict__ A, const u16* __restrict__ Bw,
                                                const float* __restrict__ bias, float* __restrict__ outp) {
  __shared__ u16 As[128 * 32];
  __shared__ u16 Bs[128 * 32];
  gemm_body<2>(A, Bw, bias, (void*)outp, As, Bs);
}

// ---- Flash attention (S^T formulation), paired q-tiles, VGPR-pipelined. ----
// K/V tile for iter kt+1 is loaded into VGPRs right after iter kt's tiles are
// published to LDS, so HBM/L2 latency flies behind QK/softmax/PV compute.
constexpr int KSTR = 136;  // K-tile row stride (u16), 17 x 16B groups
constexpr int VSTR = 72;   // V/P row stride (u16), 9 x 16B groups

__global__ __launch_bounds__(256) void attn_kernel(const u16* __restrict__ Q,
                                                   const u16* __restrict__ Kc,
                                                   const u16* __restrict__ Vt,
                                                   u16* __restrict__ O) {
  __shared__ u16 Ks[64 * KSTR];        // [krow][d]
  __shared__ u16 Vs[128 * VSTR];       // [d][krow]
  __shared__ u16 Ps[4 * 16 * VSTR];    // per-wave P strip [q][krow]
  const int tid = threadIdx.x;
  const int wave = tid >> 6;
  const int lane = tid & 63;
  const int quad = lane >> 4;
  const int l16 = lane & 15;
  const int lo = blockIdx.x;
  const int hi = 31 - lo;
  const int bh = blockIdx.y;
  const int b = bh >> 4;
  const int h = bh & 15;

  const int tIdx[2] = {lo, hi};

  // resident Q fragments (used as B-operand: B[k=d][n=q=l16])
  bf16x8 qf[2][4];
#pragma unroll
  for (int t = 0; t < 2; t++) {
    const u16* Qp = Q + (size_t)(b * T_ + tIdx[t] * 64 + wave * 16 + l16) * D_ + h * HD_;
#pragma unroll
    for (int kc = 0; kc < 4; kc++)
      qf[t][kc] = *(const bf16x8*)(Qp + kc * 32 + quad * 8);
  }

  f32x4 o[2][8] = {};
  float mrow[2], lrow[2];
#pragma unroll
  for (int t = 0; t < 2; t++) { mrow[t] = -__builtin_huge_valf(); lrow[t] = 0.f; }

  // per-lane staging base pointers
  const u16* kptr = Kc + (size_t)(b * T_) * D_ + h * HD_ + (size_t)(tid >> 4) * D_ + (tid & 15) * 8;
  const u16* vptr = Vt + (size_t)((b * H_ + h) * HD_) * T_ + (size_t)(tid >> 3) * T_ + (tid & 7) * 8;
  u16* Pw = &Ps[wave * 16 * VSTR];

  // prologue: load kt=0 tile into VGPRs
  uint4 kv[4], vv[4];
#pragma unroll
  for (int rr = 0; rr < 4; rr++)
    kv[rr] = *(const uint4*)(kptr + (size_t)(rr * 16) * D_);
#pragma unroll
  for (int rr = 0; rr < 4; rr++)
    vv[rr] = *(const uint4*)(vptr + (size_t)(rr * 32) * T_);

  for (int kt = 0; kt <= hi; kt++) {
    __syncthreads();   // prior iter's LDS reads done before overwrite
    {
      const int krow = tid >> 4, kc16 = tid & 15;
      const int vrow = tid >> 3, vc16 = tid & 7;
#pragma unroll
      for (int rr = 0; rr < 4; rr++)
        *(uint4*)&Ks[(rr * 16 + krow) * KSTR + kc16 * 8] = kv[rr];
#pragma unroll
      for (int rr = 0; rr < 4; rr++)
        *(uint4*)&Vs[(rr * 32 + vrow) * VSTR + vc16 * 8] = vv[rr];
    }
    __syncthreads();   // tiles visible to all waves

    // prefetch next tile (latency hidden behind the compute below)
    if (kt < hi) {
      const u16* kn = kptr + (size_t)(kt + 1) * 64 * D_;
      const u16* vn = vptr + (size_t)(kt + 1) * 64;
#pragma unroll
      for (int rr = 0; rr < 4; rr++)
        kv[rr] = *(const uint4*)(kn + (size_t)(rr * 16) * D_);
#pragma unroll
      for (int rr = 0; rr < 4; rr++)
        vv[rr] = *(const uint4*)(vn + (size_t)(rr * 32) * T_);
    }

#pragma unroll
    for (int t = 0; t < 2; t++) {
      if (t == 0 && kt > lo) continue;   // lo tile done (block-uniform)

      // S^T = K·Q^T: C layout -> col=l16 is q, row=quad*4+r is kcol
      f32x4 st[4];
#pragma unroll
      for (int nt = 0; nt < 4; nt++) {
        f32x4 a = {};
#pragma unroll
        for (int kc = 0; kc < 4; kc++) {
          bf16x8 kf = *(const bf16x8*)&Ks[(nt * 16 + l16) * KSTR + kc * 32 + quad * 8];
          a = __builtin_amdgcn_mfma_f32_16x16x32_bf16(kf, qf[t][kc], a, 0, 0, 0);
        }
        st[nt] = a;
      }

      const bool diag = (kt == tIdx[t]);
#pragma unroll
      for (int nt = 0; nt < 4; nt++)
#pragma unroll
        for (int r = 0; r < 4; r++) {
          float v = st[nt][r] * SL2E;
          if (diag) {
            const int kcol = nt * 16 + quad * 4 + r;
            const int qrow = wave * 16 + l16;
            if (kcol > qrow) v = -__builtin_huge_valf();
          }
          st[nt][r] = v;
        }

      // online softmax: all 16 st values of this lane share q = l16
      float mx = st[0][0];
#pragma unroll
      for (int nt = 0; nt < 4; nt++)
#pragma unroll
        for (int r = 0; r < 4; r++) mx = fmaxf(mx, st[nt][r]);
      mx = fmaxf(mx, __shfl_xor(mx, 16));
      mx = fmaxf(mx, __shfl_xor(mx, 32));
      const float mnew = fmaxf(mrow[t], mx);
      const float alpha = fexp2(mrow[t] - mnew);
      mrow[t] = mnew;
      float sum = 0.f;
#pragma unroll
      for (int nt = 0; nt < 4; nt++)
#pragma unroll
        for (int r = 0; r < 4; r++) {
          const float p = fexp2(st[nt][r] - mnew);
          st[nt][r] = p;
          sum += p;
        }
      sum += __shfl_xor(sum, 16);
      sum += __shfl_xor(sum, 32);
      lrow[t] = lrow[t] * alpha + sum;

      float af[4];
#pragma unroll
      for (int r = 0; r < 4; r++) af[r] = __shfl(alpha, quad * 4 + r);
#pragma unroll
      for (int dt = 0; dt < 8; dt++)
#pragma unroll
        for (int r = 0; r < 4; r++)
          o[t][dt][r] *= af[r];

      // P store: [q=l16][k = nt*16 + quad*4 + r]
#pragma unroll
      for (int nt = 0; nt < 4; nt++) {
        ushort4 pk;
        pk.x = f2bf(st[nt][0]); pk.y = f2bf(st[nt][1]);
        pk.z = f2bf(st[nt][2]); pk.w = f2bf(st[nt][3]);
        *(ushort4*)&Pw[l16 * VSTR + nt * 16 + quad * 4] = pk;
      }
      // wave-private strip: in-wave lgkmcnt ordering suffices (no barrier)

      bf16x8 pf[2];
#pragma unroll
      for (int kc = 0; kc < 2; kc++)
        pf[kc] = *(const bf16x8*)&Pw[l16 * VSTR + kc * 32 + quad * 8];
#pragma unroll
      for (int dt = 0; dt < 8; dt++) {
#pragma unroll
        for (int kc = 0; kc < 2; kc++) {
          bf16x8 vf = *(const bf16x8*)&Vs[(dt * 16 + l16) * VSTR + kc * 32 + quad * 8];
          o[t][dt] = __builtin_amdgcn_mfma_f32_16x16x32_bf16(pf[kc], vf, o[t][dt], 0, 0, 0);
        }
      }
    }
  }

#pragma unroll
  for (int t = 0; t < 2; t++) {
    float linv[4];
#pragma unroll
    for (int r = 0; r < 4; r++) linv[r] = 1.f / __shfl(lrow[t], quad * 4 + r);
#pragma unroll
    for (int dt = 0; dt < 8; dt++)
#pragma unroll
      for (int r = 0; r < 4; r++) {
        const int rowg = b * T_ + tIdx[t] * 64 + wave * 16 + quad * 4 + r;
        const int col = h * HD_ + dt * 16 + l16;
        O[(size_t)rowg * D_ + col] = f2bf(o[t][dt][r] * linv[r]);
      }
  }
}

extern "C" void kernel_launch(void* const* d_in, const int* in_sizes, int n_in,
                              void* d_out, int out_size, void* d_ws, size_t ws_size,
                              hipStream_t stream) {
  (void)in_sizes; (void)n_in; (void)out_size; (void)ws_size;
  const float* x  = (const float*)d_in[0];
  const float* wq = (const float*)d_in[2];
  const float* bq = (const float*)d_in[3];
  const float* wk = (const float*)d_in[4];
  const float* bk = (const float*)d_in[5];
  const float* wv = (const float*)d_in[6];
  const float* bv = (const float*)d_in[7];
  const float* wo = (const float*)d_in[8];
  const float* bo = (const float*)d_in[9];

  u16* ws  = (u16*)d_ws;
  u16* xb  = ws;                 // 8388608
  u16* wqb = ws + 8388608;
  u16* wkb = ws + 12582912;
  u16* wvb = ws + 16777216;
  u16* wob = ws + 20971520;
  u16* Qb  = ws + 25165824;
  u16* Kb  = ws + 33554432;
  u16* Vtb = ws + 41943040;      // [B,H,HD,T]
  u16* Ob  = ws + 50331648;

  cvt_kernel<<<8192, 256, 0, stream>>>(x, xb, 8388608);
  cvt4_kernel<<<dim3(4096, 4), 256, 0, stream>>>(wq, wk, wv, wo, wqb, wkb, wvb, wob, 4194304);

  dim3 gg(ND / 128, MROWS / 128, 3);
  gemm_qkv<<<gg, 256, 0, stream>>>(xb, wqb, wkb, wvb, bq, bk, bv, Qb, Kb, Vtb);
  attn_kernel<<<dim3(16, B_ * H_), 256, 0, stream>>>(Qb, Kb, Vtb, Ob);
  gemm_out<<<dim3(ND / 128, MROWS / 128), 256, 0, stream>>>(Ob, wob, bo, (float*)d_out);
}

// Round 5
// 395.011 us; speedup vs baseline: 1.2240x; 1.2240x over previous
//
#include <hip/hip_runtime.h>

typedef unsigned short u16;
typedef __bf16 bf16x8 __attribute__((ext_vector_type(8)));
typedef float f32x4 __attribute__((ext_vector_type(4)));

constexpr int B_ = 2, T_ = 2048, D_ = 2048, H_ = 16, HD_ = 128;
constexpr int MROWS = B_ * T_;   // 4096
constexpr int KD = D_;
constexpr int ND = D_;
// softmax in exp2 domain: logits pre-scaled by 1/sqrt(128) * log2(e)
#define SL2E (0.08838834764831845f * 1.4426950408889634f)

__device__ __forceinline__ u16 f2bf(float f) {
  unsigned u = __float_as_uint(f);
  u += 0x7FFF + ((u >> 16) & 1);   // RNE; inputs never NaN
  return (u16)(u >> 16);
}

__device__ __forceinline__ float fexp2(float x) { return __builtin_amdgcn_exp2f(x); }

// async global->LDS, 16B per lane; dest = wave-uniform base + lane*16
__device__ __forceinline__ void async16(const void* g, void* l) {
  __builtin_amdgcn_global_load_lds((__attribute__((address_space(1))) void*)g,
                                   (__attribute__((address_space(3))) void*)l,
                                   16, 0, 0);
}

__global__ void cvt_kernel(const float* __restrict__ in, u16* __restrict__ out, int n) {
  int i = (blockIdx.x * blockDim.x + threadIdx.x) * 4;
  if (i >= n) return;
  const float4 v = *(const float4*)(in + i);
  ushort4 h;
  h.x = f2bf(v.x); h.y = f2bf(v.y); h.z = f2bf(v.z); h.w = f2bf(v.w);
  *(ushort4*)(out + i) = h;
}

__global__ void cvt4_kernel(const float* __restrict__ w0, const float* __restrict__ w1,
                            const float* __restrict__ w2, const float* __restrict__ w3,
                            u16* __restrict__ o0, u16* __restrict__ o1,
                            u16* __restrict__ o2, u16* __restrict__ o3, int n) {
  const float* in = blockIdx.y == 0 ? w0 : blockIdx.y == 1 ? w1 : blockIdx.y == 2 ? w2 : w3;
  u16* out = blockIdx.y == 0 ? o0 : blockIdx.y == 1 ? o1 : blockIdx.y == 2 ? o2 : o3;
  int i = (blockIdx.x * blockDim.x + threadIdx.x) * 4;
  if (i >= n) return;
  const float4 v = *(const float4*)(in + i);
  ushort4 h;
  h.x = f2bf(v.x); h.y = f2bf(v.y); h.z = f2bf(v.z); h.w = f2bf(v.w);
  *(ushort4*)(out + i) = h;
}

// ---- GEMM core (unchanged from R3: conflicts == 0, m97-plateau) ----
template <int MODE>
__device__ __forceinline__ void gemm_body(const u16* __restrict__ A,
                                          const u16* __restrict__ Bw,
                                          const float* __restrict__ bias,
                                          void* __restrict__ outp,
                                          u16* As, u16* Bs) {
  constexpr int BK = 32;
  const int tid = threadIdx.x;
  const int wave = tid >> 6;
  const int lane = tid & 63;
  const int quad = lane >> 4;
  const int l16 = lane & 15;
  const int wm = (wave >> 1) * 64;
  const int wn = (wave & 1) * 64;
  const int mBase = blockIdx.y * 128;
  const int nBase = blockIdx.x * 128;

  f32x4 acc[4][4] = {};

  const int srow = wave * 32 + (lane >> 2);
  const int soff = ((lane & 3) ^ ((lane >> 3) & 3)) * 8;
  const u16* Ag = A + (size_t)(mBase + srow) * KD + soff;
  const u16* Bg = Bw + (size_t)(nBase + srow) * KD + soff;
  u16* AsW0 = &As[(wave * 32) * BK];
  u16* AsW1 = &As[(wave * 32 + 16) * BK];
  u16* BsW0 = &Bs[(wave * 32) * BK];
  u16* BsW1 = &Bs[(wave * 32 + 16) * BK];

  const int sw = (quad ^ ((l16 >> 1) & 3)) * 8;

  for (int k0 = 0; k0 < KD; k0 += BK) {
    __syncthreads();
    async16(Ag + k0, AsW0);
    async16(Ag + 16 * KD + k0, AsW1);
    async16(Bg + k0, BsW0);
    async16(Bg + 16 * KD + k0, BsW1);
    __syncthreads();

    bf16x8 a[4], b[4];
#pragma unroll
    for (int i = 0; i < 4; i++)
      a[i] = *(const bf16x8*)&As[(wm + i * 16 + l16) * BK + sw];
#pragma unroll
    for (int j = 0; j < 4; j++)
      b[j] = *(const bf16x8*)&Bs[(wn + j * 16 + l16) * BK + sw];
#pragma unroll
    for (int i = 0; i < 4; i++)
#pragma unroll
      for (int j = 0; j < 4; j++)
        acc[i][j] = __builtin_amdgcn_mfma_f32_16x16x32_bf16(a[i], b[j], acc[i][j], 0, 0, 0);
  }

  float* outF = (float*)outp;
  u16* outH = (u16*)outp;
#pragma unroll
  for (int i = 0; i < 4; i++) {
#pragma unroll
    for (int j = 0; j < 4; j++) {
      const int col = nBase + wn + j * 16 + l16;
      const float bv = bias[col];
#pragma unroll
      for (int r = 0; r < 4; r++) {
        const int row = mBase + wm + i * 16 + quad * 4 + r;
        const float v = acc[i][j][r] + bv;
        if (MODE == 0) {
          outH[(size_t)row * ND + col] = f2bf(v);
        } else if (MODE == 1) {
          const int bb = row >> 11;
          const int t = row & (T_ - 1);
          const int h = col >> 7;
          const int d = col & (HD_ - 1);
          outH[(size_t)(((bb * H_ + h) << 7) + d) * T_ + t] = f2bf(v);
        } else {
          outF[(size_t)row * ND + col] = v;
        }
      }
    }
  }
}

__global__ __launch_bounds__(256) void gemm_qkv(const u16* __restrict__ A,
                                                const u16* __restrict__ Wq, const u16* __restrict__ Wk,
                                                const u16* __restrict__ Wv,
                                                const float* __restrict__ bq, const float* __restrict__ bk,
                                                const float* __restrict__ bv,
                                                u16* __restrict__ Qo, u16* __restrict__ Ko,
                                                u16* __restrict__ Vo) {
  __shared__ u16 As[128 * 32];
  __shared__ u16 Bs[128 * 32];
  const int z = blockIdx.z;
  const u16* Bw = z == 0 ? Wq : z == 1 ? Wk : Wv;
  const float* bias = z == 0 ? bq : z == 1 ? bk : bv;
  if (z == 2)
    gemm_body<1>(A, Bw, bias, (void*)Vo, As, Bs);
  else
    gemm_body<0>(A, Bw, bias, (void*)(z == 0 ? Qo : Ko), As, Bs);
}

__global__ __launch_bounds__(256) void gemm_out(const u16* __restrict__ A, const u16* __restrict__ Bw,
                                                const float* __restrict__ bias, float* __restrict__ outp) {
  __shared__ u16 As[128 * 32];
  __shared__ u16 Bs[128 * 32];
  gemm_body<2>(A, Bw, bias, (void*)outp, As, Bs);
}

// ---- Flash attention: S^T formulation, paired q-tiles, ASYNC LDS double-buffer. ----
// K/V tiles land via global_load_lds into buf[nxt] issued right after the
// barrier of the PREVIOUS iteration -> a full compute phase hides the load.
// No VGPR prefetch state (fixes R4's scratch-spill: WRITE_SIZE 344MB).
// LDS layouts unpadded (global_load_lds needs contiguity); XOR swizzle
// (stored chunk = g ^ (row&7)) gives conflict-free b128 column reads.
constexpr int PSTR = 72;   // P strip row stride (u16), odd 16B-group count

__global__ __launch_bounds__(256, 2) void attn_kernel(const u16* __restrict__ Q,
                                                      const u16* __restrict__ Kc,
                                                      const u16* __restrict__ Vt,
                                                      u16* __restrict__ O) {
  __shared__ u16 Ks[2][64 * 128];     // [buf][krow][d-chunk swizzled]
  __shared__ u16 Vs[2][128 * 64];     // [buf][d][krow-chunk swizzled]
  __shared__ u16 Ps[4 * 16 * PSTR];   // per-wave P strip [q][krow]
  const int tid = threadIdx.x;
  const int wave = tid >> 6;
  const int lane = tid & 63;
  const int quad = lane >> 4;
  const int l16 = lane & 15;
  const int lo = blockIdx.x;
  const int hi = 31 - lo;
  const int bh = blockIdx.y;
  const int b = bh >> 4;
  const int h = bh & 15;

  const int tIdx[2] = {lo, hi};

  // resident Q fragments (B-operand: B[k=d][n=q=l16])
  bf16x8 qf[2][4];
#pragma unroll
  for (int t = 0; t < 2; t++) {
    const u16* Qp = Q + (size_t)(b * T_ + tIdx[t] * 64 + wave * 16 + l16) * D_ + h * HD_;
#pragma unroll
    for (int kc = 0; kc < 4; kc++)
      qf[t][kc] = *(const bf16x8*)(Qp + kc * 32 + quad * 8);
  }

  f32x4 o[2][8] = {};
  float mrow[2], lrow[2];
#pragma unroll
  for (int t = 0; t < 2; t++) { mrow[t] = -__builtin_huge_valf(); lrow[t] = 0.f; }

  const u16* Kg = Kc + (size_t)(b * T_) * D_ + h * HD_;
  const u16* Vg = Vt + (size_t)((b * H_ + h) * HD_) * T_;
  u16* Pw = &Ps[wave * 16 * PSTR];
  const int swz = (l16 & 7);   // read-side row swizzle

  // staging source pointers (kt=0) + wave-uniform LDS offsets
  // K: call c stages rows [wave*16+c*4, +4), 16 lanes/row, src chunk permuted
  const u16* kgp[4];
  int klo[4];
  // V: call c stages d-rows [wave*32+c*8, +8), 8 lanes/row
  const u16* vgp[4];
  int vlo[4];
#pragma unroll
  for (int c = 0; c < 4; c++) {
    const int krl = wave * 16 + c * 4 + (lane >> 4);
    const int kch = (lane & 15) ^ (krl & 7);
    kgp[c] = Kg + (size_t)krl * D_ + kch * 8;
    klo[c] = (wave * 16 + c * 4) * 128;
    const int vrl = wave * 32 + c * 8 + (lane >> 3);
    const int vch = (lane & 7) ^ (vrl & 7);
    vgp[c] = Vg + (size_t)vrl * T_ + vch * 8;
    vlo[c] = (wave * 32 + c * 8) * 64;
  }

  // prologue: issue kt=0 into buf 0
#pragma unroll
  for (int c = 0; c < 4; c++) async16(kgp[c], &Ks[0][klo[c]]);
#pragma unroll
  for (int c = 0; c < 4; c++) async16(vgp[c], &Vs[0][vlo[c]]);

  for (int kt = 0; kt <= hi; kt++) {
    const int cur = kt & 1;
    __syncthreads();   // implicit vmcnt(0): buf[cur] tiles complete; all waves synced

    if (kt < hi) {     // issue next tile into buf[cur^1]; flies behind compute
      const int nxt = cur ^ 1;
#pragma unroll
      for (int c = 0; c < 4; c++) async16(kgp[c] + (size_t)(kt + 1) * 64 * D_, &Ks[nxt][klo[c]]);
#pragma unroll
      for (int c = 0; c < 4; c++) async16(vgp[c] + (size_t)(kt + 1) * 64, &Vs[nxt][vlo[c]]);
    }

#pragma unroll
    for (int t = 0; t < 2; t++) {
      if (t == 0 && kt > lo) continue;   // lo tile done (block-uniform)

      // S^T = K·Q^T: C layout -> col=l16 is q, row=quad*4+r is kcol
      f32x4 st[4];
#pragma unroll
      for (int nt = 0; nt < 4; nt++) {
        f32x4 a = {};
#pragma unroll
        for (int kc = 0; kc < 4; kc++) {
          const int pos = (kc * 4 + quad) ^ swz;
          bf16x8 kf = *(const bf16x8*)&Ks[cur][(nt * 16 + l16) * 128 + pos * 8];
          a = __builtin_amdgcn_mfma_f32_16x16x32_bf16(kf, qf[t][kc], a, 0, 0, 0);
        }
        st[nt] = a;
      }

      const bool diag = (kt == tIdx[t]);
#pragma unroll
      for (int nt = 0; nt < 4; nt++)
#pragma unroll
        for (int r = 0; r < 4; r++) {
          float v = st[nt][r] * SL2E;
          if (diag) {
            const int kcol = nt * 16 + quad * 4 + r;
            const int qrow = wave * 16 + l16;
            if (kcol > qrow) v = -__builtin_huge_valf();
          }
          st[nt][r] = v;
        }

      // online softmax: all 16 st values of this lane share q = l16
      float mx = st[0][0];
#pragma unroll
      for (int nt = 0; nt < 4; nt++)
#pragma unroll
        for (int r = 0; r < 4; r++) mx = fmaxf(mx, st[nt][r]);
      mx = fmaxf(mx, __shfl_xor(mx, 16));
      mx = fmaxf(mx, __shfl_xor(mx, 32));
      const float mnew = fmaxf(mrow[t], mx);
      const float alpha = fexp2(mrow[t] - mnew);
      mrow[t] = mnew;
      float sum = 0.f;
#pragma unroll
      for (int nt = 0; nt < 4; nt++)
#pragma unroll
        for (int r = 0; r < 4; r++) {
          const float p = fexp2(st[nt][r] - mnew);
          st[nt][r] = p;
          sum += p;
        }
      sum += __shfl_xor(sum, 16);
      sum += __shfl_xor(sum, 32);
      lrow[t] = lrow[t] * alpha + sum;

      float af[4];
#pragma unroll
      for (int r = 0; r < 4; r++) af[r] = __shfl(alpha, quad * 4 + r);
#pragma unroll
      for (int dt = 0; dt < 8; dt++)
#pragma unroll
        for (int r = 0; r < 4; r++)
          o[t][dt][r] *= af[r];

      // P store: [q=l16][k = nt*16 + quad*4 + r]
#pragma unroll
      for (int nt = 0; nt < 4; nt++) {
        ushort4 pk;
        pk.x = f2bf(st[nt][0]); pk.y = f2bf(st[nt][1]);
        pk.z = f2bf(st[nt][2]); pk.w = f2bf(st[nt][3]);
        *(ushort4*)&Pw[l16 * PSTR + nt * 16 + quad * 4] = pk;
      }
      // wave-private strip: in-wave lgkmcnt ordering suffices (no barrier)

      bf16x8 pf[2];
#pragma unroll
      for (int kc = 0; kc < 2; kc++)
        pf[kc] = *(const bf16x8*)&Pw[l16 * PSTR + kc * 32 + quad * 8];
#pragma unroll
      for (int dt = 0; dt < 8; dt++) {
#pragma unroll
        for (int kc = 0; kc < 2; kc++) {
          const int pos = (kc * 4 + quad) ^ swz;
          bf16x8 vf = *(const bf16x8*)&Vs[cur][(dt * 16 + l16) * 64 + pos * 8];
          o[t][dt] = __builtin_amdgcn_mfma_f32_16x16x32_bf16(pf[kc], vf, o[t][dt], 0, 0, 0);
        }
      }
    }
  }

#pragma unroll
  for (int t = 0; t < 2; t++) {
    float linv[4];
#pragma unroll
    for (int r = 0; r < 4; r++) linv[r] = 1.f / __shfl(lrow[t], quad * 4 + r);
#pragma unroll
    for (int dt = 0; dt < 8; dt++)
#pragma unroll
      for (int r = 0; r < 4; r++) {
        const int rowg = b * T_ + tIdx[t] * 64 + wave * 16 + quad * 4 + r;
        const int col = h * HD_ + dt * 16 + l16;
        O[(size_t)rowg * D_ + col] = f2bf(o[t][dt][r] * linv[r]);
      }
  }
}

extern "C" void kernel_launch(void* const* d_in, const int* in_sizes, int n_in,
                              void* d_out, int out_size, void* d_ws, size_t ws_size,
                              hipStream_t stream) {
  (void)in_sizes; (void)n_in; (void)out_size; (void)ws_size;
  const float* x  = (const float*)d_in[0];
  const float* wq = (const float*)d_in[2];
  const float* bq = (const float*)d_in[3];
  const float* wk = (const float*)d_in[4];
  const float* bk = (const float*)d_in[5];
  const float* wv = (const float*)d_in[6];
  const float* bv = (const float*)d_in[7];
  const float* wo = (const float*)d_in[8];
  const float* bo = (const float*)d_in[9];

  u16* ws  = (u16*)d_ws;
  u16* xb  = ws;                 // 8388608
  u16* wqb = ws + 8388608;
  u16* wkb = ws + 12582912;
  u16* wvb = ws + 16777216;
  u16* wob = ws + 20971520;
  u16* Qb  = ws + 25165824;
  u16* Kb  = ws + 33554432;
  u16* Vtb = ws + 41943040;      // [B,H,HD,T]
  u16* Ob  = ws + 50331648;

  cvt_kernel<<<8192, 256, 0, stream>>>(x, xb, 8388608);
  cvt4_kernel<<<dim3(4096, 4), 256, 0, stream>>>(wq, wk, wv, wo, wqb, wkb, wvb, wob, 4194304);

  dim3 gg(ND / 128, MROWS / 128, 3);
  gemm_qkv<<<gg, 256, 0, stream>>>(xb, wqb, wkb, wvb, bq, bk, bv, Qb, Kb, Vtb);
  attn_kernel<<<dim3(16, B_ * H_), 256, 0, stream>>>(Qb, Kb, Vtb, Ob);
  gemm_out<<<dim3(ND / 128, MROWS / 128), 256, 0, stream>>>(Ob, wob, bo, (float*)d_out);
}